// Round 8
// baseline (332.347 us; speedup 1.0000x reference)
//
#include <hip/hip_runtime.h>

#define Bsz 4
#define Cin 64
#define C2c 128
#define Hh 256
#define Ww 256
#define Tt 16
#define HW (Hh*Ww)
#define PLANE (Bsz*4*HW)

typedef __attribute__((ext_vector_type(8))) short bf16x8;
typedef __attribute__((ext_vector_type(4))) float f32x4;

// ws layout (bytes): packed weights only (~200 KB; xT and h eliminated)
#define WBF_OFF 0
#define WTB_OFF 147456
#define AUB_OFF 163840

// LDS record strides (shorts). XP=76 x-view records (8B-aligned b64).
// HP=136: h-view records 16B-aligned -> phase2 single ds_read_b128.
#define XP 76
#define HP 136

__device__ __forceinline__ unsigned short f2bf(float f) {
  union { float f; unsigned u; } cv; cv.f = f;
  unsigned u = cv.u;
  unsigned r = (u + 0x7fffu + ((u >> 16) & 1u)) >> 16;   // RNE
  return (unsigned short)r;
}

union U8 { uint2 u2[2]; uint4 u4; bf16x8 v; };

// ---------- prep: Wtb + Wbf + Aub in one launch ----------
__global__ void prep_kernel(const float* __restrict__ W_out, const float* __restrict__ masks,
                            const float* __restrict__ Wc, const float* __restrict__ W_aue,
                            unsigned short* __restrict__ Wtb, unsigned short* __restrict__ Wbf,
                            unsigned short* __restrict__ Aub) {
  int i = blockIdx.x * 256 + threadIdx.x;
  if (i < 8192) {                                   // Wtb[to][c]
    int to = i >> 7, c = i & 127;
    int t = to >> 2, o = to & 3;
    Wtb[i] = f2bf(W_out[o * C2c + c] * masks[t * C2c + c]);
  } else if (i < 8192 + 73728) {                    // Wbf frag-ordered
    int idx = i - 8192;
    int j = idx & 7;
    int lane = (idx >> 3) & 63;
    int nt = (idx >> 9) & 7;
    int c = idx >> 12;
    int q = lane >> 4;
    int tap = c >> 1;
    int ic = (c & 1) * 32 + q * 8 + j;
    int n = nt * 16 + (lane & 15);
    Wbf[idx] = f2bf(Wc[((size_t)n * Cin + ic) * 9 + tap]);
  } else if (i < 8192 + 73728 + 18432) {            // Aub[m][k], rows>=4 zero
    int idx = i - 8192 - 73728;
    int m = idx / 1152, k = idx % 1152;
    int tap = k >> 7, c = k & 127;
    float v = (m < 4) ? W_aue[((size_t)m * C2c + c) * 9 + tap] : 0.f;
    Aub[idx] = f2bf(v);
  }
}

// ---------- fused: x staging (f32->bf16) -> conv1 MFMA -> h in LDS -> GEMV+AU+stats ----------
__global__ __launch_bounds__(256, 3) void fused_kernel(
    const float* __restrict__ x, const unsigned short* __restrict__ Wbf,
    const unsigned short* __restrict__ Wtb, const unsigned short* __restrict__ Aub,
    const float* __restrict__ bc, const float* __restrict__ b_out,
    const float* __restrict__ b_aue, const float* __restrict__ lms,
    float* __restrict__ out) {
  __shared__ unsigned short sh[192 * HP];            // 52224 B (3 blocks/CU)
  const int tid = threadIdx.x;
  const int x0 = blockIdx.x * 16, y0 = blockIdx.y * 8, bi = blockIdx.z;

  // ---- stage x-patch directly from f32 NCHW: 12 rows x 20 cols x 64 ic ----
  // thread = (ic = tid&63, xr); lane-consecutive ic -> contiguous b16 LDS writes (2-way, free).
  // Global: each lane reads 20 sequential floats of its row; L1 re-hits lines across xc.
  {
    const int ic = tid & 63;
    const int xr0 = tid >> 6;                        // 0..3
    #pragma unroll
    for (int rr = 0; rr < 3; ++rr) {
      const int xr = xr0 * 3 + rr;                   // 0..11
      const int gy = y0 - 2 + xr;
      const bool rowok = (unsigned)gy < Hh;
      const float* src = x + (((size_t)bi * Cin + ic) * Hh + gy) * Ww;
      const int lbase = (xr * 20) * XP + ic;
      #pragma unroll
      for (int xc = 0; xc < 20; ++xc) {
        const int gx = x0 - 2 + xc;
        float v = (rowok && (unsigned)gx < Ww) ? src[gx] : 0.f;
        sh[lbase + xc * XP] = f2bf(v);
      }
    }
  }
  __syncthreads();

  const int lane = tid & 63, wv = tid >> 6;
  const int n16 = lane & 15, q = lane >> 4;

  int xbase[3];
  #pragma unroll
  for (int s = 0; s < 3; ++s) {
    int px = (wv * 3 + s) * 16 + n16;               // 0..191 (>=180 garbage-safe)
    int pr = px / 18, pc = px % 18;
    xbase[s] = (pr * 20 + pc) * XP + q * 8;
  }

  f32x4 acc[3][8];                                   // [s=n-tile][mt=oc-tile]
  #pragma unroll
  for (int s = 0; s < 3; ++s)
    #pragma unroll
    for (int mt = 0; mt < 8; ++mt) acc[s][mt] = (f32x4){0.f, 0.f, 0.f, 0.f};

  // ---- phase 1 K-loop: 18 chunks, no barriers ----
  #pragma unroll
  for (int c = 0; c < 18; ++c) {
    const int tap = c >> 1, ichalf = (c & 1) * 32;
    const int dy = tap / 3, dx = tap % 3;
    const int xoff = (dy * 20 + dx) * XP + ichalf;
    bf16x8 xfr[3];
    #pragma unroll
    for (int s = 0; s < 3; ++s) {
      U8 t;
      int e = xbase[s] + xoff;
      t.u2[0] = *(const uint2*)(&sh[e]);
      t.u2[1] = *(const uint2*)(&sh[e + 4]);
      xfr[s] = t.v;
    }
    #pragma unroll
    for (int mh = 0; mh < 2; ++mh) {
      bf16x8 wfr[4];
      const unsigned short* wb = Wbf + ((size_t)(c * 8 + mh * 4) * 64 + lane) * 8;
      #pragma unroll
      for (int i4 = 0; i4 < 4; ++i4)
        wfr[i4] = ((const U8*)(wb + i4 * 512))->v;
      #pragma unroll
      for (int s = 0; s < 3; ++s)
        #pragma unroll
        for (int i4 = 0; i4 < 4; ++i4)
          acc[s][mh * 4 + i4] =
            __builtin_amdgcn_mfma_f32_16x16x32_bf16(wfr[i4], xfr[s], acc[s][mh * 4 + i4], 0, 0, 0);
    }
  }
  __syncthreads();                                   // x-view dead; reuse as h-view

  // ---- write h-patch to LDS; out-of-image h-pixels ZERO (AU conv zero-pads h) ----
  #pragma unroll
  for (int s = 0; s < 3; ++s) {
    const int px = (wv * 3 + s) * 16 + n16;
    const int pr = px / 18, pc = px % 18;
    const int gy = y0 - 1 + pr, gx = x0 - 1 + pc;
    const bool valid = ((unsigned)gy < Hh) && ((unsigned)gx < Ww);
    #pragma unroll
    for (int mt = 0; mt < 8; ++mt) {
      const int oc0 = mt * 16 + q * 4;
      const float4 b4 = *(const float4*)(bc + oc0);
      ushort4 o4;
      o4.x = valid ? f2bf(acc[s][mt][0] + b4.x) : (unsigned short)0;
      o4.y = valid ? f2bf(acc[s][mt][1] + b4.y) : (unsigned short)0;
      o4.z = valid ? f2bf(acc[s][mt][2] + b4.z) : (unsigned short)0;
      o4.w = valid ? f2bf(acc[s][mt][3] + b4.w) : (unsigned short)0;
      *(ushort4*)(&sh[px * HP + oc0]) = o4;
    }
  }
  __syncthreads();

  // ---- phase 2: GEMV + AU from LDS h-view (single b128 reads, HP=136) ----
  f32x4 accG[2][4];
  f32x4 accA[2];
  #pragma unroll
  for (int nt = 0; nt < 2; ++nt) {
    accA[nt] = (f32x4){0.f, 0.f, 0.f, 0.f};
    #pragma unroll
    for (int mt = 0; mt < 4; ++mt) accG[nt][mt] = (f32x4){0.f, 0.f, 0.f, 0.f};
  }

  #pragma unroll
  for (int kc = 0; kc < 4; ++kc) {
    bf16x8 afr[4];
    #pragma unroll
    for (int mt = 0; mt < 4; ++mt)
      afr[mt] = ((const U8*)(Wtb + (size_t)(mt * 16 + n16) * C2c + kc * 32 + q * 8))->v;
    #pragma unroll
    for (int nt = 0; nt < 2; ++nt) {
      int e = (((wv * 2 + nt) + 1) * 18 + n16 + 1) * HP + kc * 32 + q * 8;
      U8 b; b.u4 = *(const uint4*)(&sh[e]);
      #pragma unroll
      for (int mt = 0; mt < 4; ++mt)
        accG[nt][mt] = __builtin_amdgcn_mfma_f32_16x16x32_bf16(afr[mt], b.v, accG[nt][mt], 0, 0, 0);
    }
  }

  #pragma unroll
  for (int kc = 0; kc < 36; ++kc) {
    const int tap = kc >> 2, co = (kc & 3) * 32;
    const int dy = tap / 3, dx = tap % 3;
    bf16x8 afr = ((const U8*)(Aub + (size_t)n16 * 1152 + kc * 32 + q * 8))->v;
    #pragma unroll
    for (int nt = 0; nt < 2; ++nt) {
      int e = ((wv * 2 + nt + dy) * 18 + n16 + dx) * HP + co + q * 8;
      U8 b; b.u4 = *(const uint4*)(&sh[e]);
      accA[nt] = __builtin_amdgcn_mfma_f32_16x16x32_bf16(afr, b.v, accA[nt], 0, 0, 0);
    }
  }

  // ---- stats: lane holds to = mt*16 + q*4 + r -> t=4mt+q, o=r ----
  const float b0 = b_out[0], b1 = b_out[1], b2 = b_out[2], b3 = b_out[3];
  const float ba = b_aue[q];
  const int px = x0 + n16;
  #pragma unroll
  for (int nt = 0; nt < 2; ++nt) {
    const int y = y0 + wv * 2 + nt;
    float th[4][4];
    #pragma unroll
    for (int mt = 0; mt < 4; ++mt) {
      #pragma unroll
      for (int r = 0; r < 4; ++r) {
        float bo = (r == 0) ? b0 : (r == 1) ? b1 : (r == 2) ? b2 : b3;
        float v = accG[nt][mt][r] + bo;
        float e = __expf(2.f * v);
        th[mt][r] = 1.f - 2.f / (e + 1.f);           // tanh(v)
      }
    }
    float mean_r[4], eu_r[4];
    #pragma unroll
    for (int r = 0; r < 4; ++r) {
      float s = th[0][r] + th[1][r] + th[2][r] + th[3][r];
      s += __shfl_xor(s, 16);
      s += __shfl_xor(s, 32);
      float m = s * (1.f / 16.f);
      float d0 = th[0][r] - m, d1 = th[1][r] - m, d2 = th[2][r] - m, d3 = th[3][r] - m;
      float vs = d0 * d0 + d1 * d1 + d2 * d2 + d3 * d3;
      vs += __shfl_xor(vs, 16);
      vs += __shfl_xor(vs, 32);
      mean_r[r] = m;
      eu_r[r] = vs * (1.f / 15.f);                   // ddof=1
    }
    float au_r[4];
    #pragma unroll
    for (int r = 0; r < 4; ++r) au_r[r] = __shfl(accA[nt][r], n16);

    float m_q  = (q == 0) ? mean_r[0] : (q == 1) ? mean_r[1] : (q == 2) ? mean_r[2] : mean_r[3];
    float eu_q = (q == 0) ? eu_r[0]   : (q == 1) ? eu_r[1]   : (q == 2) ? eu_r[2]   : eu_r[3];
    float au_q = (q == 0) ? au_r[0]   : (q == 1) ? au_r[1]   : (q == 2) ? au_r[2]   : au_r[3];
    au_q = 1.f / (1.f + __expf(-(au_q + ba)));
    size_t oidx = ((size_t)(bi * 4 + q)) * HW + (size_t)y * Ww + px;
    float lm = lms[oidx];
    out[oidx] = au_q;
    out[PLANE + oidx] = eu_q;
    out[2 * (size_t)PLANE + oidx] = m_q + lm;
  }
}

extern "C" void kernel_launch(void* const* d_in, const int* in_sizes, int n_in,
                              void* d_out, int out_size, void* d_ws, size_t ws_size,
                              hipStream_t stream) {
  const float* x      = (const float*)d_in[0];
  const float* lms    = (const float*)d_in[1];
  const float* W_conv = (const float*)d_in[2];
  const float* b_conv = (const float*)d_in[3];
  const float* W_out  = (const float*)d_in[4];
  const float* b_out  = (const float*)d_in[5];
  const float* W_aue  = (const float*)d_in[6];
  const float* b_aue  = (const float*)d_in[7];
  const float* masks  = (const float*)d_in[8];
  float* out = (float*)d_out;

  char* ws = (char*)d_ws;
  unsigned short* Wbf = (unsigned short*)(ws + WBF_OFF);
  unsigned short* Wtb = (unsigned short*)(ws + WTB_OFF);
  unsigned short* Aub = (unsigned short*)(ws + AUB_OFF);

  prep_kernel<<<dim3(392), dim3(256), 0, stream>>>(W_out, masks, W_conv, W_aue, Wtb, Wbf, Aub);
  fused_kernel<<<dim3(16, 32, 4), dim3(256), 0, stream>>>(x, Wbf, Wtb, Aub, b_conv,
                                                          b_out, b_aue, lms, out);
}

// Round 9
// 227.064 us; speedup vs baseline: 1.4637x; 1.4637x over previous
//
#include <hip/hip_runtime.h>

#define Bsz 4
#define Cin 64
#define C2c 128
#define Hh 256
#define Ww 256
#define Tt 16
#define HW (Hh*Ww)
#define PLANE (Bsz*4*HW)

typedef __attribute__((ext_vector_type(8))) short bf16x8;
typedef __attribute__((ext_vector_type(4))) float f32x4;

// ws layout (bytes):
//   xT   (bf16) : 0        .. 33554432   [bi][y][x][ic:64]
//   Wbf  (bf16) : 33554432 .. +147456    frag-ordered conv weights
//   Wtb  (bf16) : 33701888 .. +16384     [to:64][c:128]
//   Aub  (bf16) : 33718272 .. +36864     [m:16][k:1152]
#define XT_OFF  0
#define WBF_OFF 33554432
#define WTB_OFF 33701888
#define AUB_OFF 33718272

// LDS record strides (shorts). XP=72: 144-B x-records -> 16B-aligned b128 frags.
// HP=136: 272-B h-records -> 16B-aligned b128 phase-2 reads.
#define XP 72
#define HP 136

__device__ __forceinline__ unsigned short f2bf(float f) {
  union { float f; unsigned u; } cv; cv.f = f;
  unsigned u = cv.u;
  unsigned r = (u + 0x7fffu + ((u >> 16) & 1u)) >> 16;   // RNE
  return (unsigned short)r;
}

union U8 { uint2 u2[2]; uint4 u4; bf16x8 v; };

// ---------- prep: Wtb + Wbf + Aub in one launch ----------
__global__ void prep_kernel(const float* __restrict__ W_out, const float* __restrict__ masks,
                            const float* __restrict__ Wc, const float* __restrict__ W_aue,
                            unsigned short* __restrict__ Wtb, unsigned short* __restrict__ Wbf,
                            unsigned short* __restrict__ Aub) {
  int i = blockIdx.x * 256 + threadIdx.x;
  if (i < 8192) {                                   // Wtb[to][c]
    int to = i >> 7, c = i & 127;
    int t = to >> 2, o = to & 3;
    Wtb[i] = f2bf(W_out[o * C2c + c] * masks[t * C2c + c]);
  } else if (i < 8192 + 73728) {                    // Wbf frag-ordered
    int idx = i - 8192;
    int j = idx & 7;
    int lane = (idx >> 3) & 63;
    int nt = (idx >> 9) & 7;
    int c = idx >> 12;
    int q = lane >> 4;
    int tap = c >> 1;
    int ic = (c & 1) * 32 + q * 8 + j;
    int n = nt * 16 + (lane & 15);
    Wbf[idx] = f2bf(Wc[((size_t)n * Cin + ic) * 9 + tap]);
  } else if (i < 8192 + 73728 + 18432) {            // Aub[m][k], rows>=4 zero
    int idx = i - 8192 - 73728;
    int m = idx / 1152, k = idx % 1152;
    int tap = k >> 7, c = k & 127;
    float v = (m < 4) ? W_aue[((size_t)m * C2c + c) * 9 + tap] : 0.f;
    Aub[idx] = f2bf(v);
  }
}

// ---------- x [bi][ic][y][x] f32 -> xT [bi][y][x][ic] bf16 (coalesced transpose) ----------
__global__ __launch_bounds__(256) void xt_kernel(const float* __restrict__ x,
                                                 unsigned short* __restrict__ xT) {
  __shared__ unsigned short xs[64][65];
  const int tid = threadIdx.x;
  const int x0 = blockIdx.x * 64, y = blockIdx.y, bi = blockIdx.z;
  const int tx = tid & 63, ti = tid >> 6;
  #pragma unroll
  for (int i = 0; i < 16; ++i) {
    int ic = ti * 16 + i;
    float v = x[(((size_t)bi * Cin + ic) * Hh + y) * Ww + x0 + tx];
    xs[ic][tx] = f2bf(v);
  }
  __syncthreads();
  const int icg = tid & 7, xl = tid >> 3;
  #pragma unroll
  for (int rep = 0; rep < 2; ++rep) {
    int xx = xl + 32 * rep;
    unsigned short u[8];
    #pragma unroll
    for (int k = 0; k < 8; ++k) u[k] = xs[icg * 8 + k][xx];
    *(uint4*)(xT + (((size_t)bi * Hh + y) * Ww + (x0 + xx)) * Cin + icg * 8) = *(uint4*)u;
  }
}

// ---------- fused: stage xT -> conv1 MFMA -> h in LDS -> GEMV + AU + stats ----------
// Phase-1 split: wave = 4 oc-tiles (mh) x 6 px-tiles (s6) -> Wbf loads 72/wave (was 144).
__global__ __launch_bounds__(256, 3) void fused_kernel(
    const unsigned short* __restrict__ xT, const unsigned short* __restrict__ Wbf,
    const unsigned short* __restrict__ Wtb, const unsigned short* __restrict__ Aub,
    const float* __restrict__ bc, const float* __restrict__ b_out,
    const float* __restrict__ b_aue, const float* __restrict__ lms,
    float* __restrict__ out) {
  __shared__ unsigned short sh[192 * HP];            // 52224 B (3 blocks/CU)
  const int tid = threadIdx.x;
  const int x0 = blockIdx.x * 16, y0 = blockIdx.y * 8, bi = blockIdx.z;

  // ---- stage x-patch: 12 rows x 20 cols x 8 ic-groups, b128 global -> b128 LDS ----
  for (int g = tid; g < 12 * 20 * 8; g += 256) {
    int icg = g & 7;
    int xc = (g >> 3) % 20;
    int xr = g / 160;
    int gy = y0 - 2 + xr, gx = x0 - 2 + xc;
    uint4 v = make_uint4(0, 0, 0, 0);
    if ((unsigned)gy < Hh && (unsigned)gx < Ww)
      v = *(const uint4*)(xT + (((size_t)bi * Hh + gy) * Ww + gx) * Cin + icg * 8);
    *(uint4*)(&sh[(xr * 20 + xc) * XP + icg * 8]) = v;   // 16B-aligned (XP=72)
  }
  __syncthreads();

  const int lane = tid & 63, wv = tid >> 6;
  const int n16 = lane & 15, q = lane >> 4;
  const int mh = wv & 1;                             // oc-half: mt = mh*4 + i4
  const int s6 = wv >> 1;                            // px-group: s = s6*6 + ss

  int xbase[6];
  #pragma unroll
  for (int ss = 0; ss < 6; ++ss) {
    int px = (s6 * 6 + ss) * 16 + n16;               // 0..191 (>=180 scratch)
    int pr = px / 18, pc = px % 18;
    xbase[ss] = (pr * 20 + pc) * XP + q * 8;
  }

  f32x4 acc[6][4];                                   // [ss][i4]
  #pragma unroll
  for (int ss = 0; ss < 6; ++ss)
    #pragma unroll
    for (int i4 = 0; i4 < 4; ++i4) acc[ss][i4] = (f32x4){0.f, 0.f, 0.f, 0.f};

  // ---- phase 1 K-loop: 18 chunks, no barriers ----
  #pragma unroll
  for (int c = 0; c < 18; ++c) {
    const int tap = c >> 1, ichalf = (c & 1) * 32;
    const int dy = tap / 3, dx = tap % 3;
    const int xoff = (dy * 20 + dx) * XP + ichalf;
    bf16x8 wfr[4];                                   // A: weights (global, L2)
    const unsigned short* wb = Wbf + ((size_t)(c * 8 + mh * 4) * 64 + lane) * 8;
    #pragma unroll
    for (int i4 = 0; i4 < 4; ++i4)
      wfr[i4] = ((const U8*)(wb + i4 * 512))->v;
    #pragma unroll
    for (int ss = 0; ss < 6; ++ss) {
      U8 b; b.u4 = *(const uint4*)(&sh[xbase[ss] + xoff]);   // single b128
      #pragma unroll
      for (int i4 = 0; i4 < 4; ++i4)
        acc[ss][i4] = __builtin_amdgcn_mfma_f32_16x16x32_bf16(wfr[i4], b.v, acc[ss][i4], 0, 0, 0);
    }
  }
  __syncthreads();                                   // x-view dead; reuse as h-view

  // ---- write h-patch to LDS; out-of-image h-pixels ZERO (AU conv zero-pads h) ----
  #pragma unroll
  for (int ss = 0; ss < 6; ++ss) {
    const int px = (s6 * 6 + ss) * 16 + n16;
    const int pr = px / 18, pc = px % 18;
    const int gy = y0 - 1 + pr, gx = x0 - 1 + pc;
    const bool valid = ((unsigned)gy < Hh) && ((unsigned)gx < Ww);
    #pragma unroll
    for (int i4 = 0; i4 < 4; ++i4) {
      const int oc0 = (mh * 4 + i4) * 16 + q * 4;
      const float4 b4 = *(const float4*)(bc + oc0);
      ushort4 o4;
      o4.x = valid ? f2bf(acc[ss][i4][0] + b4.x) : (unsigned short)0;
      o4.y = valid ? f2bf(acc[ss][i4][1] + b4.y) : (unsigned short)0;
      o4.z = valid ? f2bf(acc[ss][i4][2] + b4.z) : (unsigned short)0;
      o4.w = valid ? f2bf(acc[ss][i4][3] + b4.w) : (unsigned short)0;
      *(ushort4*)(&sh[px * HP + oc0]) = o4;
    }
  }
  __syncthreads();

  // ---- phase 2: GEMV + AU from LDS h-view (single b128 reads, HP=136) ----
  f32x4 accG[2][4];
  f32x4 accA[2];
  #pragma unroll
  for (int nt = 0; nt < 2; ++nt) {
    accA[nt] = (f32x4){0.f, 0.f, 0.f, 0.f};
    #pragma unroll
    for (int mt = 0; mt < 4; ++mt) accG[nt][mt] = (f32x4){0.f, 0.f, 0.f, 0.f};
  }

  #pragma unroll
  for (int kc = 0; kc < 4; ++kc) {
    bf16x8 afr[4];
    #pragma unroll
    for (int mt = 0; mt < 4; ++mt)
      afr[mt] = ((const U8*)(Wtb + (size_t)(mt * 16 + n16) * C2c + kc * 32 + q * 8))->v;
    #pragma unroll
    for (int nt = 0; nt < 2; ++nt) {
      int e = (((wv * 2 + nt) + 1) * 18 + n16 + 1) * HP + kc * 32 + q * 8;
      U8 b; b.u4 = *(const uint4*)(&sh[e]);
      #pragma unroll
      for (int mt = 0; mt < 4; ++mt)
        accG[nt][mt] = __builtin_amdgcn_mfma_f32_16x16x32_bf16(afr[mt], b.v, accG[nt][mt], 0, 0, 0);
    }
  }

  #pragma unroll
  for (int kc = 0; kc < 36; ++kc) {
    const int tap = kc >> 2, co = (kc & 3) * 32;
    const int dy = tap / 3, dx = tap % 3;
    bf16x8 afr = ((const U8*)(Aub + (size_t)n16 * 1152 + kc * 32 + q * 8))->v;
    #pragma unroll
    for (int nt = 0; nt < 2; ++nt) {
      int e = ((wv * 2 + nt + dy) * 18 + n16 + dx) * HP + co + q * 8;
      U8 b; b.u4 = *(const uint4*)(&sh[e]);
      accA[nt] = __builtin_amdgcn_mfma_f32_16x16x32_bf16(afr, b.v, accA[nt], 0, 0, 0);
    }
  }

  // ---- stats: lane holds to = mt*16 + q*4 + r -> t=4mt+q, o=r ----
  const float b0 = b_out[0], b1 = b_out[1], b2 = b_out[2], b3 = b_out[3];
  const float ba = b_aue[q];
  const int px = x0 + n16;
  #pragma unroll
  for (int nt = 0; nt < 2; ++nt) {
    const int y = y0 + wv * 2 + nt;
    float th[4][4];
    #pragma unroll
    for (int mt = 0; mt < 4; ++mt) {
      #pragma unroll
      for (int r = 0; r < 4; ++r) {
        float bo = (r == 0) ? b0 : (r == 1) ? b1 : (r == 2) ? b2 : b3;
        float v = accG[nt][mt][r] + bo;
        float e = __expf(2.f * v);
        th[mt][r] = 1.f - 2.f / (e + 1.f);           // tanh(v)
      }
    }
    float mean_r[4], eu_r[4];
    #pragma unroll
    for (int r = 0; r < 4; ++r) {
      float s = th[0][r] + th[1][r] + th[2][r] + th[3][r];
      s += __shfl_xor(s, 16);
      s += __shfl_xor(s, 32);
      float m = s * (1.f / 16.f);
      float d0 = th[0][r] - m, d1 = th[1][r] - m, d2 = th[2][r] - m, d3 = th[3][r] - m;
      float vs = d0 * d0 + d1 * d1 + d2 * d2 + d3 * d3;
      vs += __shfl_xor(vs, 16);
      vs += __shfl_xor(vs, 32);
      mean_r[r] = m;
      eu_r[r] = vs * (1.f / 15.f);                   // ddof=1
    }
    float au_r[4];
    #pragma unroll
    for (int r = 0; r < 4; ++r) au_r[r] = __shfl(accA[nt][r], n16);

    float m_q  = (q == 0) ? mean_r[0] : (q == 1) ? mean_r[1] : (q == 2) ? mean_r[2] : mean_r[3];
    float eu_q = (q == 0) ? eu_r[0]   : (q == 1) ? eu_r[1]   : (q == 2) ? eu_r[2]   : eu_r[3];
    float au_q = (q == 0) ? au_r[0]   : (q == 1) ? au_r[1]   : (q == 2) ? au_r[2]   : au_r[3];
    au_q = 1.f / (1.f + __expf(-(au_q + ba)));
    size_t oidx = ((size_t)(bi * 4 + q)) * HW + (size_t)y * Ww + px;
    float lm = lms[oidx];
    out[oidx] = au_q;
    out[PLANE + oidx] = eu_q;
    out[2 * (size_t)PLANE + oidx] = m_q + lm;
  }
}

extern "C" void kernel_launch(void* const* d_in, const int* in_sizes, int n_in,
                              void* d_out, int out_size, void* d_ws, size_t ws_size,
                              hipStream_t stream) {
  const float* x      = (const float*)d_in[0];
  const float* lms    = (const float*)d_in[1];
  const float* W_conv = (const float*)d_in[2];
  const float* b_conv = (const float*)d_in[3];
  const float* W_out  = (const float*)d_in[4];
  const float* b_out  = (const float*)d_in[5];
  const float* W_aue  = (const float*)d_in[6];
  const float* b_aue  = (const float*)d_in[7];
  const float* masks  = (const float*)d_in[8];
  float* out = (float*)d_out;

  char* ws = (char*)d_ws;
  unsigned short* xT  = (unsigned short*)(ws + XT_OFF);
  unsigned short* Wbf = (unsigned short*)(ws + WBF_OFF);
  unsigned short* Wtb = (unsigned short*)(ws + WTB_OFF);
  unsigned short* Aub = (unsigned short*)(ws + AUB_OFF);

  prep_kernel<<<dim3(392), dim3(256), 0, stream>>>(W_out, masks, W_conv, W_aue, Wtb, Wbf, Aub);
  xt_kernel<<<dim3(4, 256, 4), dim3(256), 0, stream>>>(x, xT);
  fused_kernel<<<dim3(16, 32, 4), dim3(256), 0, stream>>>(xT, Wbf, Wtb, Aub, b_conv,
                                                          b_out, b_aue, lms, out);
}